// Round 1
// baseline (31.278 us; speedup 1.0000x reference)
//
#include <hip/hip_runtime.h>

#define DIMS 64
#define KF 16

__global__ __launch_bounds__(256, 2) void fm_fwd_kernel(
    const int* __restrict__ user,
    const int* __restrict__ item,
    const float* __restrict__ user_emb,
    const float* __restrict__ item_emb,
    const float* __restrict__ w1,
    const float* __restrict__ b1,
    const float* __restrict__ v,
    float* __restrict__ out,
    int B)
{
    const int lane = threadIdx.x & 63;
    const int wv   = threadIdx.x >> 6;
    const int row  = blockIdx.x * 4 + wv;
    if (row >= B) return;

    const int u  = user[row];
    const int it = item[row];

    // x[lane] from user row, x[64+lane] from item row — coalesced 256B segments
    const float xa = user_emb[(size_t)u  * DIMS + lane];
    const float xb = item_emb[(size_t)it * DIMS + lane];

    // v rows for elements `lane` and `64+lane` (v is [128][16] row-major, 8KB total, L1-hot)
    const float4* va4 = (const float4*)(v + (size_t)lane * KF);
    const float4* vb4 = (const float4*)(v + (size_t)(DIMS + lane) * KF);
    float va[KF], vb[KF];
    #pragma unroll
    for (int i = 0; i < 4; ++i) {
        float4 a = va4[i], b = vb4[i];
        va[4*i+0]=a.x; va[4*i+1]=a.y; va[4*i+2]=a.z; va[4*i+3]=a.w;
        vb[4*i+0]=b.x; vb[4*i+1]=b.y; vb[4*i+2]=b.z; vb[4*i+3]=b.w;
    }
    const float wa = w1[lane], wb = w1[DIMS + lane];

    // Per-lane partials: s[k] over this lane's 2 elements; t summed over k locally.
    float s[KF];
    const float xa2 = xa * xa, xb2 = xb * xb;
    float t = 0.f;
    #pragma unroll
    for (int k = 0; k < KF; ++k) {
        s[k] = xa * va[k] + xb * vb[k];
        t   += xa2 * va[k] * va[k] + xb2 * vb[k] * vb[k];
    }
    float lin = xa * wa + xb * wb;

    // Vector-halving butterfly: masks 1,2,4,8. After this each lane holds
    // S_{bitrev4(lane&15)} summed over its 16-lane block (15 shuffles total).
    int n = KF;
    #pragma unroll
    for (int step = 0; step < 4; ++step) {
        n >>= 1;
        const int m = 1 << step;
        const bool hi = (lane & m) != 0;
        #pragma unroll
        for (int i = 0; i < n; ++i) {
            float keep = hi ? s[n + i] : s[i];
            float send = hi ? s[i] : s[n + i];
            float recv = __shfl_xor(send, m, 64);
            s[i] = keep + recv;
        }
    }
    // Finish summing S_k over the 4 blocks of 16 lanes.
    float sv = s[0];
    sv += __shfl_xor(sv, 16, 64);
    sv += __shfl_xor(sv, 32, 64);
    float val = sv * sv;   // S_k^2; each distinct k appears exactly 4x across the wave

    // Joint 6-step butterfly for {val, t, lin}
    #pragma unroll
    for (int m = 1; m < 64; m <<= 1) {
        val += __shfl_xor(val, m, 64);
        t   += __shfl_xor(t,   m, 64);
        lin += __shfl_xor(lin, m, 64);
    }
    // sum(val over 64 lanes) = 4 * sum_k S_k^2

    if (lane == 0) {
        out[row] = lin + b1[0] + 0.5f * (0.25f * val - t);
    }
}

extern "C" void kernel_launch(void* const* d_in, const int* in_sizes, int n_in,
                              void* d_out, int out_size, void* d_ws, size_t ws_size,
                              hipStream_t stream) {
    const int*   user     = (const int*)  d_in[0];
    const int*   item     = (const int*)  d_in[1];
    const float* user_emb = (const float*)d_in[2];
    const float* item_emb = (const float*)d_in[3];
    const float* w1       = (const float*)d_in[4];
    const float* b1       = (const float*)d_in[5];
    const float* v        = (const float*)d_in[6];
    float* out = (float*)d_out;

    const int B = in_sizes[0];
    const int blocks = (B + 3) / 4;   // 4 waves (rows) per 256-thread block
    fm_fwd_kernel<<<blocks, 256, 0, stream>>>(user, item, user_emb, item_emb,
                                              w1, b1, v, out, B);
}